// Round 7
// baseline (212.664 us; speedup 1.0000x reference)
//
#include <hip/hip_runtime.h>
#include <hip/hip_bf16.h>
#include <stdint.h>

#define M_DIM 16384   // 8 * 2048
#define N_DIM 2048    // OUT_F
#define K_DIM 2048    // IN_F

typedef __attribute__((ext_vector_type(8))) __bf16 bf16x8;
typedef __attribute__((ext_vector_type(4))) float f32x4;

__device__ __forceinline__ unsigned short f2bf(float f) {
  unsigned int u = __builtin_bit_cast(unsigned int, f);
  u += 0x7FFFu + ((u >> 16) & 1u);   // round-to-nearest-even
  return (unsigned short)(u >> 16);
}

__device__ __forceinline__ float sigmoidf_(float x) {
  return 1.0f / (1.0f + __expf(-x));
}

// ---------------- kernel 1: X f32 -> bf16 ----------------
__global__ __launch_bounds__(256) void convert_x(const float4* __restrict__ x,
                                                 uint4* __restrict__ xb) {
  int idx = blockIdx.x * 256 + threadIdx.x;   // one uint4 (8 bf16) per thread
  float4 a = x[idx * 2];
  float4 b = x[idx * 2 + 1];
  uint4 r;
  r.x = (unsigned)f2bf(a.x) | ((unsigned)f2bf(a.y) << 16);
  r.y = (unsigned)f2bf(a.z) | ((unsigned)f2bf(a.w) << 16);
  r.z = (unsigned)f2bf(b.x) | ((unsigned)f2bf(b.y) << 16);
  r.w = (unsigned)f2bf(b.z) | ((unsigned)f2bf(b.w) << 16);
  xb[idx] = r;
}

// ---------------- kernel 2: weight materialization (producer-aligned) -------
// XCD x (blockIdx%8) materializes exactly B panel o in [x*256, x*256+256) --
// the panel GEMM-XCD x reads (B stays dirty-resident in its birth L2).
__global__ __launch_bounds__(256) void make_w(const float4* __restrict__ pw,
                                              const float4* __restrict__ nw,
                                              const float* __restrict__ exps,
                                              const float* __restrict__ maskw,
                                              const float* __restrict__ scale,
                                              unsigned short* __restrict__ wout) {
  const int beta = blockIdx.x;          // 16384 blocks
  const int xcd = beta & 7;
  const int j = beta >> 3;              // 0..2047
  const int o = xcd * 256 + (j >> 3);   // output row (B panel row)
  const int iblk = j & 7;               // 256-wide i chunk
  int idx = (o * 2048 + iblk * 256) + threadIdx.x;   // flat (o*K + i) in float4s
  float4 p = pw[idx];
  float4 n = nw[idx];
  float s = scale[0];
  float c0 = sigmoidf_(maskw[0]) * exps[0] * s;
  float c1 = sigmoidf_(maskw[1]) * exps[1] * s;
  float c2 = sigmoidf_(maskw[2]) * exps[2] * s;
  float c3 = sigmoidf_(maskw[3]) * exps[3] * s;
  float w = (sigmoidf_(p.x) - sigmoidf_(n.x)) * c0
          + (sigmoidf_(p.y) - sigmoidf_(n.y)) * c1
          + (sigmoidf_(p.z) - sigmoidf_(n.z)) * c2
          + (sigmoidf_(p.w) - sigmoidf_(n.w)) * c3;
  wout[idx] = f2bf(w);
}

// ---------------- kernel 3: bias ----------------
__global__ __launch_bounds__(256) void make_bias(const float* __restrict__ pb,
                                                 const float* __restrict__ nb,
                                                 const float* __restrict__ bexps,
                                                 const float* __restrict__ bscale,
                                                 float* __restrict__ bias) {
  int o = blockIdx.x * 256 + threadIdx.x;
  if (o < N_DIM) {
    float x = 0.f;
#pragma unroll
    for (int n = 0; n < 4; ++n) x += (pb[o * 4 + n] - nb[o * 4 + n]) * bexps[n];
    float xc = fminf(fmaxf(x, -1.f), 1.f);
    float mag = rintf(fabsf(xc) * 15.f) * (1.f / 15.f);
    float sgn = (xc > 0.f) ? 1.f : ((xc < 0.f) ? -1.f : 0.f);
    bias[o] = mag * sgn * bscale[0];
  }
}

// ---------------- kernel 4: 256x256 GEMM, deep-slack rotated staging --------
// R6 post-mortem: gates had only 2-phase (~1100cy) slack vs ~600-900cy+queue
// load-return latency. Rotate staging one phase earlier so every gate is a
// uniform VMCNT(6) with 3-4 phases of slack (m201's constant), still 2 LDS
// buffers:
//   P0(t): stage R2R3(t+1)->q   P1(t): stage R4R5(t+1)->q
//   P2(t): stage R6R7(t+1)->q   P3(t): stage R0R1(t+2)->p  (region released
//                                       by P0(t)'s reads, 3 barriers earlier)
// Reads: P0: a0<-R0R1, b01<-R2R3 (tile t); P1: b23<-R4R5; P2: a1<-R6R7; P3: -
// MFMA:  P0:(0,0)=a0*b01  P1:(0,1)=a0*b23  P2:(1,0)=a1*b01  P3:(1,1)=a1*b23
// Gates (all VMCNT(6), derived from issue stream):
//   end-P0 retires R4R5(t) [3-phase slack]; end-P1 retires R6R7(t) [3];
//   end-P2 none; end-P3 retires R0R1(t+1)+R2R3(t+1) [4-phase slack].
// Max 10 in flight, never drained. No mid-phase barrier (R6 win kept).
// Tail: wrapped-index junk staging into dead buffers keeps counts uniform.

#define BM 256
#define BN 256
#define BK 64
#define NT (K_DIM / BK)   // 32

__device__ __forceinline__ void gload16(const void* g, void* l) {
  __builtin_amdgcn_global_load_lds(
      (const __attribute__((address_space(1))) unsigned int*)g,
      (__attribute__((address_space(3))) unsigned int*)l, 16, 0, 0);
}

#define VMCNT(n) asm volatile("s_waitcnt vmcnt(" #n ")" ::: "memory")
#define BAR() __builtin_amdgcn_s_barrier()

__global__ __launch_bounds__(512, 2) void gemm_bias(const unsigned short* __restrict__ X,
                                                    const unsigned short* __restrict__ W,
                                                    const float* __restrict__ bias,
                                                    float* __restrict__ out) {
  __shared__ unsigned short sA[2][BM * BK];   // 64 KiB
  __shared__ unsigned short sB[2][BN * BK];   // 64 KiB

  const int tid = threadIdx.x;
  // Locality swizzle (R5, kept): one bn-column per XCD; B panel L2-private.
  const int bn = (int)blockIdx.x & 7;    // == XCD (dispatch round-robin)
  const int bm = (int)blockIdx.x >> 3;   // 0..63
  const int row0 = bm * BM, col0 = bn * BN;

  const int w = tid >> 6, l = tid & 63;
  const int wr = w >> 2;        // 0..1  (M wave group)
  const int wc = w & 3;         // 0..3  (N wave group)
  const int lr = l & 15;
  const int lk4 = l >> 4;       // 0..3
  const int l7 = l & 7;

  const unsigned short* Ag = X + (size_t)row0 * K_DIM;
  const unsigned short* Bg = W + (size_t)col0 * K_DIM;

  // staging geometry: thread t -> row rb+((t>>3)&31); global col16 pre-swizzled
  const int srl = (tid >> 3) & 31;
  const int sc16 = (tid & 7) ^ ((tid >> 3) & 7);      // inverse-swizzled source
  const int shi = tid >> 8;                           // wave-uniform chunk select
  const int slin = ((tid >> 3) & 24) * 64 + (tid & 63) * 8;  // linear LDS dest

  auto stage = [&](unsigned short* lbase, const unsigned short* gbase,
                   int rb0, int rb1, int tk) {
    int rb = shi ? rb1 : rb0;
    int trow = rb + srl;
    gload16(gbase + (size_t)trow * K_DIM + tk * BK + sc16 * 8,
            lbase + rb * 64 + slin);
  };

  auto rdA = [&](const unsigned short* base, int mf, int ks) -> bf16x8 {
    int trow = wr * 128 + mf * 16 + lr;
    int c16l = (ks * 4 + lk4) ^ l7;
    return *(const bf16x8*)&base[trow * 64 + c16l * 8];
  };
  auto rdB = [&](const unsigned short* base, int nf, int ks) -> bf16x8 {
    int trow = wc * 64 + nf * 16 + lr;
    int c16l = (ks * 4 + lk4) ^ l7;
    return *(const bf16x8*)&base[trow * 64 + c16l * 8];
  };

  f32x4 acc[8][4] = {};
  bf16x8 a[4][2], b[4][2];

#define PHASE_MFMA(mh, nh)                                                    \
  __builtin_amdgcn_s_setprio(1);                                              \
  _Pragma("unroll") for (int i = 0; i < 4; ++i)                               \
  _Pragma("unroll") for (int j = 0; j < 2; ++j)                               \
  _Pragma("unroll") for (int ks = 0; ks < 2; ++ks)                            \
      acc[(mh) * 4 + i][(nh) * 2 + j] = __builtin_amdgcn_mfma_f32_16x16x32_bf16( \
          a[i][ks], b[(nh) * 2 + j][ks], acc[(mh) * 4 + i][(nh) * 2 + j], 0, 0, 0); \
  __builtin_amdgcn_s_setprio(0);

  // ---- prologue: R0-R7(0)->buf0, R0R1(1)->buf1  (10 loads, issue order fixed)
  stage(sA[0], Ag, 0, 32, 0);     // R0(0)
  stage(sA[0], Ag, 128, 160, 0);  // R1(0)
  stage(sB[0], Bg, 0, 64, 0);     // R2(0)
  stage(sB[0], Bg, 128, 192, 0);  // R3(0)
  stage(sB[0], Bg, 32, 96, 0);    // R4(0)
  stage(sB[0], Bg, 160, 224, 0);  // R5(0)
  stage(sA[0], Ag, 64, 96, 0);    // R6(0)
  stage(sA[0], Ag, 192, 224, 0);  // R7(0)
  stage(sA[1], Ag, 0, 32, 1);     // R0(1)
  stage(sA[1], Ag, 128, 160, 1);  // R1(1)
  VMCNT(6);   // R0-R3(0) complete (matches steady end-P3 gate)
  BAR();

  for (int t = 0; t < NT; ++t) {
    const int p = t & 1, q = p ^ 1;
    const int t1 = (t + 1) & (NT - 1);   // wrapped tail: uniform vmcnt counts
    const int t2 = (t + 2) & (NT - 1);
    const unsigned short* pa = sA[p];
    const unsigned short* pb = sB[p];

    // ---- P0: read a0+b01(t); stage R2R3(t+1)->q; MFMA (0,0)
#pragma unroll
    for (int i = 0; i < 4; ++i)
#pragma unroll
      for (int ks = 0; ks < 2; ++ks) a[i][ks] = rdA(pa, i, ks);
#pragma unroll
    for (int j = 0; j < 2; ++j)
#pragma unroll
      for (int ks = 0; ks < 2; ++ks) b[j][ks] = rdB(pb, j, ks);
    stage(sB[q], Bg, 0, 64, t1);     // R2(t+1)
    stage(sB[q], Bg, 128, 192, t1);  // R3(t+1)
    PHASE_MFMA(0, 0);
    VMCNT(6);                        // retires R4R5(t)  [3-phase slack]
    BAR();

    // ---- P1: read b23(t); stage R4R5(t+1)->q; MFMA (0,1)
#pragma unroll
    for (int j = 2; j < 4; ++j)
#pragma unroll
      for (int ks = 0; ks < 2; ++ks) b[j][ks] = rdB(pb, j, ks);
    stage(sB[q], Bg, 32, 96, t1);    // R4(t+1)
    stage(sB[q], Bg, 160, 224, t1);  // R5(t+1)
    PHASE_MFMA(0, 1);
    VMCNT(6);                        // retires R6R7(t)  [3-phase slack]
    BAR();

    // ---- P2: read a1(t); stage R6R7(t+1)->q; MFMA (1,0)
#pragma unroll
    for (int i = 0; i < 4; ++i)
#pragma unroll
      for (int ks = 0; ks < 2; ++ks) a[i][ks] = rdA(pa, 4 + i, ks);
    stage(sA[q], Ag, 64, 96, t1);    // R6(t+1)
    stage(sA[q], Ag, 192, 224, t1);  // R7(t+1)
    PHASE_MFMA(1, 0);
    BAR();                           // no gate: P3 reads nothing

    // ---- P3: stage R0R1(t+2)->p (region released by P0(t), 3 barriers ago);
    //          MFMA (1,1)
    stage(sA[p], Ag, 0, 32, t2);     // R0(t+2)
    stage(sA[p], Ag, 128, 160, t2);  // R1(t+2)
    PHASE_MFMA(1, 1);
    VMCNT(6);                        // retires R0R1(t+1)+R2R3(t+1) [4-phase]
    BAR();
  }

  // ---- epilogue: bias + store (C/D layout: col=lane&15, row=(lane>>4)*4+reg)
  float bv[4];
#pragma unroll
  for (int nf = 0; nf < 4; ++nf) bv[nf] = bias[col0 + wc * 64 + nf * 16 + lr];
  const int orow = lk4 * 4;
#pragma unroll
  for (int mf = 0; mf < 8; ++mf) {
#pragma unroll
    for (int nf = 0; nf < 4; ++nf) {
      const int colg = col0 + wc * 64 + nf * 16 + lr;
#pragma unroll
      for (int r = 0; r < 4; ++r) {
        int rowg = row0 + wr * 128 + mf * 16 + orow + r;
        out[(size_t)rowg * N_DIM + colg] = acc[mf][nf][r] + bv[nf];
      }
    }
  }
#undef PHASE_MFMA
}

// ---------------- launch ----------------
extern "C" void kernel_launch(void* const* d_in, const int* in_sizes, int n_in,
                              void* d_out, int out_size, void* d_ws, size_t ws_size,
                              hipStream_t stream) {
  const float* input  = (const float*)d_in[0];
  const float* pweight = (const float*)d_in[1];
  const float* nweight = (const float*)d_in[2];
  const float* exps   = (const float*)d_in[3];
  const float* bexps  = (const float*)d_in[4];
  const float* maskw  = (const float*)d_in[5];
  const float* scale  = (const float*)d_in[6];
  const float* pbias  = (const float*)d_in[7];
  const float* nbias  = (const float*)d_in[8];
  const float* bscale = (const float*)d_in[9];
  float* out = (float*)d_out;

  unsigned short* Xb = (unsigned short*)d_ws;                                        // 64 MB
  unsigned short* Wb = (unsigned short*)((char*)d_ws + (size_t)M_DIM * K_DIM * 2);   // 8 MB
  float* bias = (float*)((char*)d_ws + (size_t)M_DIM * K_DIM * 2 + (size_t)N_DIM * K_DIM * 2);

  convert_x<<<(M_DIM * (size_t)K_DIM) / 8 / 256, 256, 0, stream>>>((const float4*)input, (uint4*)Xb);
  make_w<<<((size_t)N_DIM * K_DIM) / 256, 256, 0, stream>>>(
      (const float4*)pweight, (const float4*)nweight, exps, maskw, scale, Wb);
  make_bias<<<(N_DIM + 255) / 256, 256, 0, stream>>>(pbias, nbias, bexps, bscale, bias);

  dim3 grid((M_DIM / BM) * (N_DIM / BN));   // 64 * 8 = 512
  gemm_bias<<<grid, 512, 0, stream>>>(Xb, Wb, bias, out);
}

// Round 8
// 201.716 us; speedup vs baseline: 1.0543x; 1.0543x over previous
//
#include <hip/hip_runtime.h>
#include <hip/hip_bf16.h>
#include <stdint.h>

#define M_DIM 16384   // 8 * 2048
#define N_DIM 2048    // OUT_F
#define K_DIM 2048    // IN_F

typedef __attribute__((ext_vector_type(8))) __bf16 bf16x8;
typedef __attribute__((ext_vector_type(4))) float f32x4;

__device__ __forceinline__ unsigned short f2bf(float f) {
  unsigned int u = __builtin_bit_cast(unsigned int, f);
  u += 0x7FFFu + ((u >> 16) & 1u);   // round-to-nearest-even
  return (unsigned short)(u >> 16);
}

__device__ __forceinline__ float sigmoidf_(float x) {
  return 1.0f / (1.0f + __expf(-x));
}

// ---------------- kernel 1: X f32 -> bf16 ----------------
__global__ __launch_bounds__(256) void convert_x(const float4* __restrict__ x,
                                                 uint4* __restrict__ xb) {
  int idx = blockIdx.x * 256 + threadIdx.x;   // one uint4 (8 bf16) per thread
  float4 a = x[idx * 2];
  float4 b = x[idx * 2 + 1];
  uint4 r;
  r.x = (unsigned)f2bf(a.x) | ((unsigned)f2bf(a.y) << 16);
  r.y = (unsigned)f2bf(a.z) | ((unsigned)f2bf(a.w) << 16);
  r.z = (unsigned)f2bf(b.x) | ((unsigned)f2bf(b.y) << 16);
  r.w = (unsigned)f2bf(b.z) | ((unsigned)f2bf(b.w) << 16);
  xb[idx] = r;
}

// ---------------- kernel 2: weight materialization (producer-aligned) -------
// XCD x (blockIdx%8) materializes exactly B panel o in [x*256, x*256+256) --
// the panel GEMM-XCD x reads (B stays dirty-resident in its birth L2).
__global__ __launch_bounds__(256) void make_w(const float4* __restrict__ pw,
                                              const float4* __restrict__ nw,
                                              const float* __restrict__ exps,
                                              const float* __restrict__ maskw,
                                              const float* __restrict__ scale,
                                              unsigned short* __restrict__ wout) {
  const int beta = blockIdx.x;          // 16384 blocks
  const int xcd = beta & 7;
  const int j = beta >> 3;              // 0..2047
  const int o = xcd * 256 + (j >> 3);   // output row (B panel row)
  const int iblk = j & 7;               // 256-wide i chunk
  int idx = (o * 2048 + iblk * 256) + threadIdx.x;   // flat (o*K + i) in float4s
  float4 p = pw[idx];
  float4 n = nw[idx];
  float s = scale[0];
  float c0 = sigmoidf_(maskw[0]) * exps[0] * s;
  float c1 = sigmoidf_(maskw[1]) * exps[1] * s;
  float c2 = sigmoidf_(maskw[2]) * exps[2] * s;
  float c3 = sigmoidf_(maskw[3]) * exps[3] * s;
  float w = (sigmoidf_(p.x) - sigmoidf_(n.x)) * c0
          + (sigmoidf_(p.y) - sigmoidf_(n.y)) * c1
          + (sigmoidf_(p.z) - sigmoidf_(n.z)) * c2
          + (sigmoidf_(p.w) - sigmoidf_(n.w)) * c3;
  wout[idx] = f2bf(w);
}

// ---------------- kernel 3: bias ----------------
__global__ __launch_bounds__(256) void make_bias(const float* __restrict__ pb,
                                                 const float* __restrict__ nb,
                                                 const float* __restrict__ bexps,
                                                 const float* __restrict__ bscale,
                                                 float* __restrict__ bias) {
  int o = blockIdx.x * 256 + threadIdx.x;
  if (o < N_DIM) {
    float x = 0.f;
#pragma unroll
    for (int n = 0; n < 4; ++n) x += (pb[o * 4 + n] - nb[o * 4 + n]) * bexps[n];
    float xc = fminf(fmaxf(x, -1.f), 1.f);
    float mag = rintf(fabsf(xc) * 15.f) * (1.f / 15.f);
    float sgn = (xc > 0.f) ? 1.f : ((xc < 0.f) ? -1.f : 0.f);
    bias[o] = mag * sgn * bscale[0];
  }
}

// ---------------- kernel 4: 256x256 GEMM, BK=32, 4-deep staged pipeline -----
// R7 post-mortem: 6 schedule variants all ~5400cy/tile because per-CU ingest
// is LATENCY x IN-FLIGHT limited: only 8-12KB of global_load_lds outstanding
// (2-buffer LDS cap) / ~1100cy mixed L3/HBM latency ~= 26 GB/s/CU, vs the
// 46 GB/s a tile needs. Fix: BK=32 tiles (32KB staged), FOUR LDS buffers
// (128 KiB), stage 3 tiles ahead -> 12 gload_lds/wave = 96KB/CU in flight.
// Per iter (one K-tile): {12 ds_read_b128; 4x gload_lds(t+3); 32 MFMA (no
// dependent chains at K=32); VMCNT(8) retires tile t+1 (2-iter slack); BAR}.
//
// LDS tile layout (A and B identical): logical (r in [0,256), k in [0,32))
//   fold_row fr = r & 127, hi = r >> 7
//   slot = ((k>>3) + 4*hi) ^ (fr & 7)          // XOR bank swizzle
//   byte = fr*128 + slot*16
// Two contiguous 8KB stage rounds per tile (fr 0..63, 64..127); gload_lds
// dest is linear (base + tid*16B), per-lane global source = inverse map
// (rule 21). Reads: 8 lanes/16B-slot = 2/bank = conflict-free (m136).

#define BM 256
#define BN 256
#define BK 32
#define NT (K_DIM / BK)   // 64
#define NBUF 4

__device__ __forceinline__ void gload16(const void* g, void* l) {
  __builtin_amdgcn_global_load_lds(
      (const __attribute__((address_space(1))) unsigned int*)g,
      (__attribute__((address_space(3))) unsigned int*)l, 16, 0, 0);
}

#define VMCNT(n) asm volatile("s_waitcnt vmcnt(" #n ")" ::: "memory")
#define BAR() __builtin_amdgcn_s_barrier()

__global__ __launch_bounds__(512, 2) void gemm_bias(const unsigned short* __restrict__ X,
                                                    const unsigned short* __restrict__ W,
                                                    const float* __restrict__ bias,
                                                    float* __restrict__ out) {
  __shared__ unsigned short sA[NBUF][128 * 64];   // 4 x 16 KiB
  __shared__ unsigned short sB[NBUF][128 * 64];   // 4 x 16 KiB  (128 KiB total)

  const int tid = threadIdx.x;
  // Locality swizzle (R5, kept): one bn-column per XCD; B panel L2-private.
  const int bn = (int)blockIdx.x & 7;    // == XCD (dispatch round-robin)
  const int bm = (int)blockIdx.x >> 3;   // 0..63
  const int row0 = bm * BM, col0 = bn * BN;

  const int w = tid >> 6, l = tid & 63;
  const int wr = w >> 2;        // 0..1  (M wave group)
  const int wc = w & 3;         // 0..3  (N wave group)
  const int lr = l & 15;
  const int lk4 = l >> 4;       // 0..3
  const int lr7 = lr & 7;

  const unsigned short* Ag = X + (size_t)row0 * K_DIM;
  const unsigned short* Bg = W + (size_t)col0 * K_DIM;

  // ---- staging: one gload_lds per thread per round (8KB round, fr rr..rr+63)
  // inverse fold map: lane tid -> fr = rr + (tid>>3), slot = tid&7,
  //   pre = slot ^ (fr&7); global r = fr + 128*(pre>>2), k = (pre&3)*8.
  const int s_frl = tid >> 3;                       // 0..63 (fr - rr)
  const int s_pre = (tid & 7) ^ ((tid >> 3) & 7);
  const int s_rglo = 128 * (s_pre >> 2);            // 0 or 128
  const int s_k = (s_pre & 3) * 8;
  const int s_dst = tid * 8;                        // us offset within round

  auto stage = [&](unsigned short* lbase, const unsigned short* gbase,
                   int rr, int tk) {
    gload16(gbase + (size_t)(rr + s_frl + s_rglo) * K_DIM + tk * BK + s_k,
            lbase + rr * 64 + s_dst);
  };

  // ---- fragment reads (conflict-free: 8 lanes per 16B slot = 2/bank)
  auto rdA = [&](const unsigned short* base, int mf) -> bf16x8 {
    int fr = mf * 16 + lr;                   // (wr*128)&127 == 0
    int slot = (lk4 + 4 * wr) ^ lr7;
    return *(const bf16x8*)&base[fr * 64 + slot * 8];
  };
  auto rdB = [&](const unsigned short* base, int nf) -> bf16x8 {
    int fr = (wc & 1) * 64 + nf * 16 + lr;
    int slot = (lk4 + 4 * (wc >> 1)) ^ lr7;
    return *(const bf16x8*)&base[fr * 64 + slot * 8];
  };

  f32x4 acc[8][4] = {};
  bf16x8 a[8], b[4];

  // ---- prologue: stage tiles 0,1,2 (12 loads/wave in flight)
#pragma unroll
  for (int pt = 0; pt < 3; ++pt) {
    stage(sA[pt], Ag, 0, pt);
    stage(sA[pt], Ag, 64, pt);
    stage(sB[pt], Bg, 0, pt);
    stage(sB[pt], Bg, 64, pt);
  }
  VMCNT(8);   // tile 0 landed
  BAR();

  for (int t = 0; t < NT; ++t) {
    const unsigned short* pa = sA[t & 3];
    const unsigned short* pb = sB[t & 3];
    unsigned short* qa = sA[(t + 3) & 3];
    unsigned short* qb = sB[(t + 3) & 3];
    const int tk3 = (t + 3) & (NT - 1);   // wrapped tail: junk into dead buf,
                                          // keeps vmcnt accounting uniform
    // reads of tile t (12 x ds_read_b128)
#pragma unroll
    for (int mf = 0; mf < 8; ++mf) a[mf] = rdA(pa, mf);
#pragma unroll
    for (int nf = 0; nf < 4; ++nf) b[nf] = rdB(pb, nf);

    // stage tile t+3 (buffer (t+3)&3 is dead: last read iter t-1, barrier ago)
    stage(qa, Ag, 0, tk3);
    stage(qa, Ag, 64, tk3);
    stage(qb, Bg, 0, tk3);
    stage(qb, Bg, 64, tk3);

    // 32 independent MFMAs (K=32: no acc chains)
    __builtin_amdgcn_s_setprio(1);
#pragma unroll
    for (int mf = 0; mf < 8; ++mf)
#pragma unroll
      for (int nf = 0; nf < 4; ++nf)
        acc[mf][nf] = __builtin_amdgcn_mfma_f32_16x16x32_bf16(
            a[mf], b[nf], acc[mf][nf], 0, 0, 0);
    __builtin_amdgcn_s_setprio(0);

    VMCNT(8);   // retires tile t+1's 4 loads (issued iter t-2: 2-iter slack)
    BAR();
  }

  // ---- epilogue: bias + store (C/D layout: col=lane&15, row=(lane>>4)*4+reg)
  float bv[4];
#pragma unroll
  for (int nf = 0; nf < 4; ++nf) bv[nf] = bias[col0 + wc * 64 + nf * 16 + lr];
  const int orow = lk4 * 4;
#pragma unroll
  for (int mf = 0; mf < 8; ++mf) {
#pragma unroll
    for (int nf = 0; nf < 4; ++nf) {
      const int colg = col0 + wc * 64 + nf * 16 + lr;
#pragma unroll
      for (int r = 0; r < 4; ++r) {
        int rowg = row0 + wr * 128 + mf * 16 + orow + r;
        out[(size_t)rowg * N_DIM + colg] = acc[mf][nf][r] + bv[nf];
      }
    }
  }
}

// ---------------- launch ----------------
extern "C" void kernel_launch(void* const* d_in, const int* in_sizes, int n_in,
                              void* d_out, int out_size, void* d_ws, size_t ws_size,
                              hipStream_t stream) {
  const float* input  = (const float*)d_in[0];
  const float* pweight = (const float*)d_in[1];
  const float* nweight = (const float*)d_in[2];
  const float* exps   = (const float*)d_in[3];
  const float* bexps  = (const float*)d_in[4];
  const float* maskw  = (const float*)d_in[5];
  const float* scale  = (const float*)d_in[6];
  const float* pbias  = (const float*)d_in[7];
  const float* nbias  = (const float*)d_in[8];
  const float* bscale = (const float*)d_in[9];
  float* out = (float*)d_out;

  unsigned short* Xb = (unsigned short*)d_ws;                                        // 64 MB
  unsigned short* Wb = (unsigned short*)((char*)d_ws + (size_t)M_DIM * K_DIM * 2);   // 8 MB
  float* bias = (float*)((char*)d_ws + (size_t)M_DIM * K_DIM * 2 + (size_t)N_DIM * K_DIM * 2);

  convert_x<<<(M_DIM * (size_t)K_DIM) / 8 / 256, 256, 0, stream>>>((const float4*)input, (uint4*)Xb);
  make_w<<<((size_t)N_DIM * K_DIM) / 256, 256, 0, stream>>>(
      (const float4*)pweight, (const float4*)nweight, exps, maskw, scale, Wb);
  make_bias<<<(N_DIM + 255) / 256, 256, 0, stream>>>(pbias, nbias, bexps, bscale, bias);

  dim3 grid((M_DIM / BM) * (N_DIM / BN));   // 64 * 8 = 512
  gemm_bias<<<grid, 512, 0, stream>>>(Xb, Wb, bias, out);
}